// Round 2
// baseline (343.983 us; speedup 1.0000x reference)
//
#include <hip/hip_runtime.h>

#define NEG 0.2f
#define CHUNK 2048   // edges per bin-fill block (256 thr x 8)
#define BINW 48      // bin slots per node; P(Poisson(16) >= 48) ~ 6e-11

using bf16x8 = __attribute__((ext_vector_type(8))) short;
using f32x4  = __attribute__((ext_vector_type(4))) float;
using f32x2  = __attribute__((ext_vector_type(2))) float;

__device__ __forceinline__ short f2bf(float f) {   // RNE round to bf16 bits
    union { float f; unsigned u; } v; v.f = f;
    unsigned r = v.u + 0x7FFFu + ((v.u >> 16) & 1u);
    return (short)(r >> 16);
}
__device__ __forceinline__ float bflo(unsigned v) {
    union { unsigned u; float f; } x; x.u = v << 16; return x.f;
}
__device__ __forceinline__ float bfhi(unsigned v) {
    union { unsigned u; float f; } x; x.u = v & 0xffff0000u; return x.f;
}

// ---------------------------------------------------------------------------
// k_wt: W (f32, [k][c]) -> bf16 transposed Wbf[c*128+k] (16 blocks), plus
// grid-stride zeroing of cnt (replaces the hipMemsetAsync dispatch).
// ---------------------------------------------------------------------------
__global__ __launch_bounds__(256) void k_wt(const float* __restrict__ W,
                                            unsigned short* __restrict__ Wbf,
                                            int* __restrict__ cnt, int N) {
    int idx = (blockIdx.x * 256 + threadIdx.x) * 4;
    #pragma unroll
    for (int q = 0; q < 4; ++q) {
        int i = idx + q;            // i = k*128 + c
        int k = i >> 7, c = i & 127;
        Wbf[c * 128 + k] = (unsigned short)f2bf(W[i]);
    }
    for (int i = blockIdx.x * 256 + threadIdx.x; i < N; i += gridDim.x * 256)
        cnt[i] = 0;
}

// ---------------------------------------------------------------------------
// k_fg (FUSED fill+gemm): blocks [0,FB) run the SINGLE-PASS bin build —
// each edge read exactly ONCE (no 8x dst-range replication: device-scope
// atomics resolve at the memory-side coherence point regardless of which
// XCD issues them, so the old range-partition only multiplied the edge
// stream reads by 8). slot = atomicAdd(cnt[d]), bins[d*48+slot] = src[e].
// Fill blocks are 5% VALU / 18% HBM / 0 MFMA -> they overlap with the GEMM
// blocks' MFMA+streaming work nearly for free; fill blocks dispatch FIRST
// so the latency-bound part starts immediately.
//
// Blocks [FB,FB+GB): h(bf16) = bf16(feats) @ W via mfma_f32_16x16x32_bf16
// with fused epilogue (el/er dots, fp8 h8 pack, coalesced uint4 h stores)
// from the barrier-guarded re-use of the Wt LDS buffer.
// ---------------------------------------------------------------------------
__global__ __launch_bounds__(256) void k_fg(const float* __restrict__ feats,
                                            const unsigned short* __restrict__ Wbf,
                                            unsigned short* __restrict__ h,
                                            const float* __restrict__ attn_l,
                                            const float* __restrict__ attn_r,
                                            float* __restrict__ el,
                                            float* __restrict__ er,
                                            unsigned char* __restrict__ h8,
                                            const int* __restrict__ src,
                                            const int* __restrict__ dst,
                                            int* __restrict__ cnt,
                                            int* __restrict__ bins,
                                            int N, int E, int FB) {
    __shared__ __align__(16) short Wt[128 * 136];   // 34816 B; re-used as h-tile

    if (blockIdx.x < FB) {
        // ---- fill path (no LDS, no barriers) ----
        int base = blockIdx.x * CHUNK + threadIdx.x;
        #pragma unroll
        for (int q = 0; q < 8; ++q) {
            int e = base + q * 256;
            if (e < E) {
                int d = dst[e];
                int s = src[e];
                int p = atomicAdd(&cnt[d], 1);
                if (p < BINW) bins[(size_t)d * BINW + p] = s;
            }
        }
        return;
    }

    // ---- gemm path ----
    const int t = threadIdx.x;
    const int n0 = (blockIdx.x - FB) * 64;

    {
        const uint4* Ws = (const uint4*)Wbf;
        #pragma unroll
        for (int i = 0; i < 8; ++i) {
            int g = t * 8 + i;            // uint4 index
            int c = g >> 4, j = g & 15;   // row c, 16 uint4 per row
            *(uint4*)&Wt[c * 136 + j * 8] = Ws[g];
        }
    }
    __syncthreads();

    const int w    = t >> 6;
    const int lane = t & 63;
    const int m    = lane & 15;
    const int quad = lane >> 4;
    const int kq   = quad * 8;

    const int row_a = n0 + w * 16 + m;
    const bool va = (row_a < N);

    f32x4 acc[8];
    #pragma unroll
    for (int ti = 0; ti < 8; ++ti) acc[ti] = (f32x4){0.f, 0.f, 0.f, 0.f};

    #pragma unroll
    for (int kc = 0; kc < 4; ++kc) {
        const float* ap = feats + (size_t)row_a * 128 + kc * 32 + kq;
        float4 a0 = va ? ((const float4*)ap)[0] : make_float4(0.f,0.f,0.f,0.f);
        float4 a1 = va ? ((const float4*)ap)[1] : make_float4(0.f,0.f,0.f,0.f);
        bf16x8 af;
        af[0] = f2bf(a0.x); af[1] = f2bf(a0.y); af[2] = f2bf(a0.z); af[3] = f2bf(a0.w);
        af[4] = f2bf(a1.x); af[5] = f2bf(a1.y); af[6] = f2bf(a1.z); af[7] = f2bf(a1.w);
        #pragma unroll
        for (int ti = 0; ti < 8; ++ti) {
            bf16x8 bf = *(const bf16x8*)&Wt[(ti * 16 + m) * 136 + kc * 32 + kq];
            acc[ti] = __builtin_amdgcn_mfma_f32_16x16x32_bf16(af, bf, acc[ti], 0, 0, 0);
        }
    }

    // ---- fused epilogue ----
    __syncthreads();                  // all Wt reads complete before re-use
    short* hs = Wt;                   // [64][136] bf16 tile, +8 pad stride
    const int row_l = w * 16 + quad * 4;
    // C layout: col = ti*16 + m, row = row_l + r
    #pragma unroll
    for (int ti = 0; ti < 8; ++ti) {
        int col = ti * 16 + m;
        #pragma unroll
        for (int r = 0; r < 4; ++r)
            hs[(row_l + r) * 136 + col] = f2bf(acc[ti][r]);
    }
    __syncthreads();

    #pragma unroll
    for (int u = 0; u < 2; ++u) {
        int p = u * 256 + t;          // 512 (row,head) pairs, 2 per thread
        int row = p >> 3, hd = p & 7;
        int rg = n0 + row;
        if (rg < N) {
            const uint4* hp = (const uint4*)&hs[row * 136 + hd * 16];
            uint4 u0 = hp[0], u1 = hp[1];

            // coalesced bf16 h store (32 B per thread)
            uint4* hg = (uint4*)(h + (size_t)rg * 128 + hd * 16);
            hg[0] = u0; hg[1] = u1;

            float hv[16];
            hv[0]=bflo(u0.x); hv[1]=bfhi(u0.x); hv[2]=bflo(u0.y); hv[3]=bfhi(u0.y);
            hv[4]=bflo(u0.z); hv[5]=bfhi(u0.z); hv[6]=bflo(u0.w); hv[7]=bfhi(u0.w);
            hv[8]=bflo(u1.x); hv[9]=bfhi(u1.x); hv[10]=bflo(u1.y); hv[11]=bfhi(u1.y);
            hv[12]=bflo(u1.z); hv[13]=bfhi(u1.z); hv[14]=bflo(u1.w); hv[15]=bfhi(u1.w);

            // fp8 gather copy: 16 values -> 16 bytes, coalesced uint4 store
            unsigned p0 = 0, p1 = 0, p2 = 0, p3 = 0;
            p0 = __builtin_amdgcn_cvt_pk_fp8_f32(hv[0],  hv[1],  p0, false);
            p0 = __builtin_amdgcn_cvt_pk_fp8_f32(hv[2],  hv[3],  p0, true);
            p1 = __builtin_amdgcn_cvt_pk_fp8_f32(hv[4],  hv[5],  p1, false);
            p1 = __builtin_amdgcn_cvt_pk_fp8_f32(hv[6],  hv[7],  p1, true);
            p2 = __builtin_amdgcn_cvt_pk_fp8_f32(hv[8],  hv[9],  p2, false);
            p2 = __builtin_amdgcn_cvt_pk_fp8_f32(hv[10], hv[11], p2, true);
            p3 = __builtin_amdgcn_cvt_pk_fp8_f32(hv[12], hv[13], p3, false);
            p3 = __builtin_amdgcn_cvt_pk_fp8_f32(hv[14], hv[15], p3, true);
            *(uint4*)(h8 + (size_t)rg * 128 + hd * 16) = make_uint4(p0, p1, p2, p3);

            const float4* al = (const float4*)(attn_l + hd * 16);
            const float4* ar = (const float4*)(attn_r + hd * 16);
            float sl = 0.f, sr = 0.f;
            #pragma unroll
            for (int q = 0; q < 4; ++q) {
                float4 a = al[q], b = ar[q];
                sl += hv[4*q]*a.x + hv[4*q+1]*a.y + hv[4*q+2]*a.z + hv[4*q+3]*a.w;
                sr += hv[4*q]*b.x + hv[4*q+1]*b.y + hv[4*q+2]*b.z + hv[4*q+3]*b.w;
            }
            el[rg * 8 + hd] = sl;
            er[rg * 8 + hd] = sr;
        }
    }
}

// ---------------------------------------------------------------------------
// k_agg: gather aggregation, one wave per node; quarter q handles bin slots
// q, q+4, ... with 4-edge unroll. Message gather from fp8 h8 (8 B/lane,
// 128 B/edge); residual from bf16 h. Bin layout: bins[n*48 + slot],
// degree = min(cnt[n], 48). Block swizzle keeps consecutive node groups
// (contiguous bins/el/h lines) on one XCD's L2.
// ---------------------------------------------------------------------------
__global__ __launch_bounds__(256) void k_agg(const int* __restrict__ cnt,
                                             const int* __restrict__ bins,
                                             const float* __restrict__ el,
                                             const float* __restrict__ er,
                                             const unsigned char* __restrict__ h8,
                                             const unsigned short* __restrict__ h,
                                             const float* __restrict__ bias,
                                             float* __restrict__ out, int N) {
    int nb = gridDim.x;
    int b  = blockIdx.x;
    int g  = ((nb & 7) == 0) ? ((b & 7) * (nb >> 3) + (b >> 3)) : b;

    int t = threadIdx.x;
    int n = g * 4 + (t >> 6);
    if (n >= N) return;
    int lane = t & 63;
    int q    = lane >> 4;      // slot phase 0..3
    int c16  = lane & 15;      // col group: cols 8*c16..8*c16+7
    int hd   = c16 >> 1;
    int deg  = cnt[n];
    if (deg > BINW) deg = BINW;
    int begin = n * BINW;
    int end   = begin + deg;
    float erv = er[n * 8 + hd];

    float acc[8] = {0.f,0.f,0.f,0.f,0.f,0.f,0.f,0.f};
    float expsum = 0.f;

    auto edge = [&](int p) {
        int s = bins[p];
        float x = el[s * 8 + hd] + erv;
        x = x > 0.f ? x : NEG * x;
        float w = __expf(x);
        expsum += w;
        uint2 hv = *(const uint2*)(h8 + (size_t)s * 128 + c16 * 8);
        f32x2 d0 = __builtin_amdgcn_cvt_pk_f32_fp8(hv.x, false);
        f32x2 d1 = __builtin_amdgcn_cvt_pk_f32_fp8(hv.x, true);
        f32x2 d2 = __builtin_amdgcn_cvt_pk_f32_fp8(hv.y, false);
        f32x2 d3 = __builtin_amdgcn_cvt_pk_f32_fp8(hv.y, true);
        acc[0] += w * d0[0]; acc[1] += w * d0[1];
        acc[2] += w * d1[0]; acc[3] += w * d1[1];
        acc[4] += w * d2[0]; acc[5] += w * d2[1];
        acc[6] += w * d3[0]; acc[7] += w * d3[1];
    };

    int p = begin + q;
    for (; p + 12 < end; p += 16) { edge(p); edge(p + 4); edge(p + 8); edge(p + 12); }
    for (; p < end; p += 4) edge(p);

    #pragma unroll
    for (int k = 0; k < 8; ++k) {
        acc[k] += __shfl_xor(acc[k], 32);
        acc[k] += __shfl_xor(acc[k], 16);
    }
    expsum += __shfl_xor(expsum, 32);
    expsum += __shfl_xor(expsum, 16);

    if (q == 0) {
        float inv = expsum > 0.f ? 1.f / expsum : 0.f;
        uint4 hn = *(const uint4*)(h + (size_t)n * 128 + c16 * 8);
        const float4* bp = (const float4*)(bias + c16 * 8);
        float4 b0 = bp[0], b1 = bp[1];
        float4 o0, o1;
        o0.x = acc[0]*inv + bflo(hn.x) + b0.x;
        o0.y = acc[1]*inv + bfhi(hn.x) + b0.y;
        o0.z = acc[2]*inv + bflo(hn.y) + b0.z;
        o0.w = acc[3]*inv + bfhi(hn.y) + b0.w;
        o1.x = acc[4]*inv + bflo(hn.z) + b1.x;
        o1.y = acc[5]*inv + bfhi(hn.z) + b1.y;
        o1.z = acc[6]*inv + bflo(hn.w) + b1.z;
        o1.w = acc[7]*inv + bfhi(hn.w) + b1.w;
        float4* op = (float4*)(out + (size_t)n * 128 + c16 * 8);
        op[0] = o0; op[1] = o1;
    }
}

extern "C" void kernel_launch(void* const* d_in, const int* in_sizes, int n_in,
                              void* d_out, int out_size, void* d_ws, size_t ws_size,
                              hipStream_t stream) {
    const float* feats  = (const float*)d_in[0];
    const float* W      = (const float*)d_in[1];
    const float* attn_l = (const float*)d_in[2];
    const float* attn_r = (const float*)d_in[3];
    const float* bias   = (const float*)d_in[4];
    const int*   src    = (const int*)d_in[5];
    const int*   dst    = (const int*)d_in[6];

    const int N  = in_sizes[0] / 128;
    const int E  = in_sizes[5];
    const int FB = (E + CHUNK - 1) / CHUNK;    // fill blocks
    const int GB = (N + 63) / 64;              // gemm blocks

    float* out = (float*)d_out;
    char*  ws  = (char*)d_ws;
    unsigned short* Wbf = (unsigned short*)ws;         ws += 128 * 128 * 2;
    unsigned short* h = (unsigned short*)ws;           ws += (size_t)N * 128 * 2;
    unsigned char* h8 = (unsigned char*)ws;            ws += (size_t)N * 128;
    float* el      = (float*)ws;                       ws += (size_t)N * 8 * 4;
    float* er      = (float*)ws;                       ws += (size_t)N * 8 * 4;
    int*   cnt     = (int*)ws;                         ws += (size_t)N * 4;
    int*   bins    = (int*)ws;                         ws += (size_t)N * BINW * 4;

    k_wt <<<16,          256, 0, stream>>>(W, Wbf, cnt, N);
    k_fg <<<FB + GB,     256, 0, stream>>>(feats, Wbf, h, attn_l, attn_r, el, er, h8,
                                           src, dst, cnt, bins, N, E, FB);
    k_agg <<<(N + 3) / 4, 256, 0, stream>>>(cnt, bins, el, er, h8, h, bias, out, N);
}

// Round 6
// 281.953 us; speedup vs baseline: 1.2200x; 1.2200x over previous
//
#include <hip/hip_runtime.h>

#define NEG 0.2f
#define CHUNK 2048   // edges per bin-fill block (256 thr x 8)
#define BINW 48      // bin slots per node; P(Poisson(16) >= 48) ~ 6e-11

using bf16x8 = __attribute__((ext_vector_type(8))) short;
using f32x4  = __attribute__((ext_vector_type(4))) float;
using f32x2  = __attribute__((ext_vector_type(2))) float;
using u32x4  = __attribute__((ext_vector_type(4))) unsigned int;

__device__ __forceinline__ short f2bf(float f) {   // RNE round to bf16 bits
    union { float f; unsigned u; } v; v.f = f;
    unsigned r = v.u + 0x7FFFu + ((v.u >> 16) & 1u);
    return (short)(r >> 16);
}
__device__ __forceinline__ float bflo(unsigned v) {
    union { unsigned u; float f; } x; x.u = v << 16; return x.f;
}
__device__ __forceinline__ float bfhi(unsigned v) {
    union { unsigned u; float f; } x; x.u = v & 0xffff0000u; return x.f;
}

// ---------------------------------------------------------------------------
// k_wt: W (f32, [k][c]) -> bf16 transposed Wbf[c*128+k] (16 blocks), plus
// grid-stride zeroing of cnt (replaces the hipMemsetAsync dispatch).
// ---------------------------------------------------------------------------
__global__ __launch_bounds__(256) void k_wt(const float* __restrict__ W,
                                            unsigned short* __restrict__ Wbf,
                                            int* __restrict__ cnt, int N) {
    int idx = (blockIdx.x * 256 + threadIdx.x) * 4;
    #pragma unroll
    for (int q = 0; q < 4; ++q) {
        int i = idx + q;            // i = k*128 + c
        int k = i >> 7, c = i & 127;
        Wbf[c * 128 + k] = (unsigned short)f2bf(W[i]);
    }
    for (int i = blockIdx.x * 256 + threadIdx.x; i < N; i += gridDim.x * 256)
        cnt[i] = 0;
}

// ---------------------------------------------------------------------------
// k_fill: SINGLE-PASS binned CSR build, dst-range partitioned (r = b&7 keeps
// each range's cnt/bins lines on ONE XCD under round-robin blockIdx->XCD
// dispatch — round-2 A/B showed removing this costs ~1.7x on the fill).
// slot = atomicAdd(cnt[d]), bins[d*48+slot] = src[e].
// NT loads on the dst/src streams: they are read-once, and keeping them out
// of L2 stops the 4x re-writeback churn of dirty bins lines (round-1
// counter: 78 MB written for a ~20 MB dirty footprint).
// Separate kernel (no LDS) so occupancy is wave-limited, not LDS-limited.
// ---------------------------------------------------------------------------
__global__ __launch_bounds__(256) void k_fill(const int* __restrict__ src,
                                              const int* __restrict__ dst,
                                              int* __restrict__ cnt,
                                              int* __restrict__ bins,
                                              int E, int N8) {
    int b = blockIdx.x;
    int r = b & 7;
    int c = b >> 3;
    int lo = r * N8, hi = lo + N8;
    int base = c * CHUNK + threadIdx.x;
    #pragma unroll
    for (int q = 0; q < 8; ++q) {
        int e = base + q * 256;
        if (e < E) {
            int d = __builtin_nontemporal_load(dst + e);
            if (d >= lo && d < hi) {
                int s = __builtin_nontemporal_load(src + e);
                int p = atomicAdd(&cnt[d], 1);
                if (p < BINW) bins[(size_t)d * BINW + p] = s;
            }
        }
    }
}

// ---------------------------------------------------------------------------
// k_gemm (fused eler): h(bf16) = bf16(feats) @ W via mfma_f32_16x16x32_bf16,
// then the epilogue runs in-block from the barrier-guarded re-use of the Wt
// LDS buffer: coalesced uint4 h stores, fp8 h8 pack, el/er dots. feats is
// streamed with NT loads (read-once, 51 MB — keep it out of L2).
// ---------------------------------------------------------------------------
__global__ __launch_bounds__(256) void k_gemm(const float* __restrict__ feats,
                                              const unsigned short* __restrict__ Wbf,
                                              unsigned short* __restrict__ h,
                                              const float* __restrict__ attn_l,
                                              const float* __restrict__ attn_r,
                                              float* __restrict__ el,
                                              float* __restrict__ er,
                                              unsigned char* __restrict__ h8,
                                              int N) {
    __shared__ __align__(16) short Wt[128 * 136];   // 34816 B; re-used as h-tile
    const int t = threadIdx.x;
    const int n0 = blockIdx.x * 64;

    {
        const uint4* Ws = (const uint4*)Wbf;
        #pragma unroll
        for (int i = 0; i < 8; ++i) {
            int g = t * 8 + i;            // uint4 index
            int c = g >> 4, j = g & 15;   // row c, 16 uint4 per row
            *(uint4*)&Wt[c * 136 + j * 8] = Ws[g];
        }
    }
    __syncthreads();

    const int w    = t >> 6;
    const int lane = t & 63;
    const int m    = lane & 15;
    const int quad = lane >> 4;
    const int kq   = quad * 8;

    const int row_a = n0 + w * 16 + m;
    const bool va = (row_a < N);

    f32x4 acc[8];
    #pragma unroll
    for (int ti = 0; ti < 8; ++ti) acc[ti] = (f32x4){0.f, 0.f, 0.f, 0.f};

    #pragma unroll
    for (int kc = 0; kc < 4; ++kc) {
        const f32x4* ap = (const f32x4*)(feats + (size_t)row_a * 128 + kc * 32 + kq);
        f32x4 a0 = (f32x4){0.f,0.f,0.f,0.f}, a1 = (f32x4){0.f,0.f,0.f,0.f};
        if (va) {
            a0 = __builtin_nontemporal_load(ap);
            a1 = __builtin_nontemporal_load(ap + 1);
        }
        bf16x8 af;
        af[0] = f2bf(a0[0]); af[1] = f2bf(a0[1]); af[2] = f2bf(a0[2]); af[3] = f2bf(a0[3]);
        af[4] = f2bf(a1[0]); af[5] = f2bf(a1[1]); af[6] = f2bf(a1[2]); af[7] = f2bf(a1[3]);
        #pragma unroll
        for (int ti = 0; ti < 8; ++ti) {
            bf16x8 bf = *(const bf16x8*)&Wt[(ti * 16 + m) * 136 + kc * 32 + kq];
            acc[ti] = __builtin_amdgcn_mfma_f32_16x16x32_bf16(af, bf, acc[ti], 0, 0, 0);
        }
    }

    // ---- fused epilogue ----
    __syncthreads();                  // all Wt reads complete before re-use
    short* hs = Wt;                   // [64][136] bf16 tile, +8 pad stride
    const int row_l = w * 16 + quad * 4;
    // C layout: col = ti*16 + m, row = row_l + r
    #pragma unroll
    for (int ti = 0; ti < 8; ++ti) {
        int col = ti * 16 + m;
        #pragma unroll
        for (int r = 0; r < 4; ++r)
            hs[(row_l + r) * 136 + col] = f2bf(acc[ti][r]);
    }
    __syncthreads();

    #pragma unroll
    for (int u = 0; u < 2; ++u) {
        int p = u * 256 + t;          // 512 (row,head) pairs, 2 per thread
        int row = p >> 3, hd = p & 7;
        int rg = n0 + row;
        if (rg < N) {
            const uint4* hp = (const uint4*)&hs[row * 136 + hd * 16];
            uint4 u0 = hp[0], u1 = hp[1];

            // coalesced bf16 h store (32 B per thread)
            uint4* hg = (uint4*)(h + (size_t)rg * 128 + hd * 16);
            hg[0] = u0; hg[1] = u1;

            float hv[16];
            hv[0]=bflo(u0.x); hv[1]=bfhi(u0.x); hv[2]=bflo(u0.y); hv[3]=bfhi(u0.y);
            hv[4]=bflo(u0.z); hv[5]=bfhi(u0.z); hv[6]=bflo(u0.w); hv[7]=bfhi(u0.w);
            hv[8]=bflo(u1.x); hv[9]=bfhi(u1.x); hv[10]=bflo(u1.y); hv[11]=bfhi(u1.y);
            hv[12]=bflo(u1.z); hv[13]=bfhi(u1.z); hv[14]=bflo(u1.w); hv[15]=bfhi(u1.w);

            // fp8 gather copy: 16 values -> 16 bytes, coalesced uint4 store
            unsigned p0 = 0, p1 = 0, p2 = 0, p3 = 0;
            p0 = __builtin_amdgcn_cvt_pk_fp8_f32(hv[0],  hv[1],  p0, false);
            p0 = __builtin_amdgcn_cvt_pk_fp8_f32(hv[2],  hv[3],  p0, true);
            p1 = __builtin_amdgcn_cvt_pk_fp8_f32(hv[4],  hv[5],  p1, false);
            p1 = __builtin_amdgcn_cvt_pk_fp8_f32(hv[6],  hv[7],  p1, true);
            p2 = __builtin_amdgcn_cvt_pk_fp8_f32(hv[8],  hv[9],  p2, false);
            p2 = __builtin_amdgcn_cvt_pk_fp8_f32(hv[10], hv[11], p2, true);
            p3 = __builtin_amdgcn_cvt_pk_fp8_f32(hv[12], hv[13], p3, false);
            p3 = __builtin_amdgcn_cvt_pk_fp8_f32(hv[14], hv[15], p3, true);
            *(uint4*)(h8 + (size_t)rg * 128 + hd * 16) = make_uint4(p0, p1, p2, p3);

            const float4* al = (const float4*)(attn_l + hd * 16);
            const float4* ar = (const float4*)(attn_r + hd * 16);
            float sl = 0.f, sr = 0.f;
            #pragma unroll
            for (int q = 0; q < 4; ++q) {
                float4 a = al[q], b = ar[q];
                sl += hv[4*q]*a.x + hv[4*q+1]*a.y + hv[4*q+2]*a.z + hv[4*q+3]*a.w;
                sr += hv[4*q]*b.x + hv[4*q+1]*b.y + hv[4*q+2]*b.z + hv[4*q+3]*b.w;
            }
            el[rg * 8 + hd] = sl;
            er[rg * 8 + hd] = sr;
        }
    }
}

// ---------------------------------------------------------------------------
// k_agg: gather aggregation, one wave per node; quarter q handles bin slots
// q, q+4, ... with 4-edge unroll. Message gather from fp8 h8 (8 B/lane,
// 128 B/edge); residual from bf16 h. Bin layout: bins[n*48 + slot],
// degree = min(cnt[n], 48). Block swizzle aligns node-range-eighth r with
// XCD r — the XCD whose L2 holds that range's bins lines from k_fill.
// NT on touch-once traffic (bins, residual h, out stores) so L2 is kept
// for the reused h8/el gather lines.
// ---------------------------------------------------------------------------
__global__ __launch_bounds__(256) void k_agg(const int* __restrict__ cnt,
                                             const int* __restrict__ bins,
                                             const float* __restrict__ el,
                                             const float* __restrict__ er,
                                             const unsigned char* __restrict__ h8,
                                             const unsigned short* __restrict__ h,
                                             const float* __restrict__ bias,
                                             float* __restrict__ out, int N) {
    int nb = gridDim.x;
    int b  = blockIdx.x;
    int g  = ((nb & 7) == 0) ? ((b & 7) * (nb >> 3) + (b >> 3)) : b;

    int t = threadIdx.x;
    int n = g * 4 + (t >> 6);
    if (n >= N) return;
    int lane = t & 63;
    int q    = lane >> 4;      // slot phase 0..3
    int c16  = lane & 15;      // col group: cols 8*c16..8*c16+7
    int hd   = c16 >> 1;
    int deg  = cnt[n];
    if (deg > BINW) deg = BINW;
    int begin = n * BINW;
    int end   = begin + deg;
    float erv = er[n * 8 + hd];

    float acc[8] = {0.f,0.f,0.f,0.f,0.f,0.f,0.f,0.f};
    float expsum = 0.f;

    auto edge = [&](int p) {
        int s = __builtin_nontemporal_load(bins + p);
        float x = el[s * 8 + hd] + erv;
        x = x > 0.f ? x : NEG * x;
        float w = __expf(x);
        expsum += w;
        uint2 hv = *(const uint2*)(h8 + (size_t)s * 128 + c16 * 8);
        f32x2 d0 = __builtin_amdgcn_cvt_pk_f32_fp8(hv.x, false);
        f32x2 d1 = __builtin_amdgcn_cvt_pk_f32_fp8(hv.x, true);
        f32x2 d2 = __builtin_amdgcn_cvt_pk_f32_fp8(hv.y, false);
        f32x2 d3 = __builtin_amdgcn_cvt_pk_f32_fp8(hv.y, true);
        acc[0] += w * d0[0]; acc[1] += w * d0[1];
        acc[2] += w * d1[0]; acc[3] += w * d1[1];
        acc[4] += w * d2[0]; acc[5] += w * d2[1];
        acc[6] += w * d3[0]; acc[7] += w * d3[1];
    };

    int p = begin + q;
    for (; p + 12 < end; p += 16) { edge(p); edge(p + 4); edge(p + 8); edge(p + 12); }
    for (; p < end; p += 4) edge(p);

    #pragma unroll
    for (int k = 0; k < 8; ++k) {
        acc[k] += __shfl_xor(acc[k], 32);
        acc[k] += __shfl_xor(acc[k], 16);
    }
    expsum += __shfl_xor(expsum, 32);
    expsum += __shfl_xor(expsum, 16);

    if (q == 0) {
        float inv = expsum > 0.f ? 1.f / expsum : 0.f;
        u32x4 hn = __builtin_nontemporal_load((const u32x4*)(h + (size_t)n * 128 + c16 * 8));
        const float4* bp = (const float4*)(bias + c16 * 8);
        float4 b0 = bp[0], b1 = bp[1];
        f32x4 o0, o1;
        o0[0] = acc[0]*inv + bflo(hn[0]) + b0.x;
        o0[1] = acc[1]*inv + bfhi(hn[0]) + b0.y;
        o0[2] = acc[2]*inv + bflo(hn[1]) + b0.z;
        o0[3] = acc[3]*inv + bfhi(hn[1]) + b0.w;
        o1[0] = acc[4]*inv + bflo(hn[2]) + b1.x;
        o1[1] = acc[5]*inv + bfhi(hn[2]) + b1.y;
        o1[2] = acc[6]*inv + bflo(hn[3]) + b1.z;
        o1[3] = acc[7]*inv + bfhi(hn[3]) + b1.w;
        f32x4* op = (f32x4*)(out + (size_t)n * 128 + c16 * 8);
        __builtin_nontemporal_store(o0, op);
        __builtin_nontemporal_store(o1, op + 1);
    }
}

extern "C" void kernel_launch(void* const* d_in, const int* in_sizes, int n_in,
                              void* d_out, int out_size, void* d_ws, size_t ws_size,
                              hipStream_t stream) {
    const float* feats  = (const float*)d_in[0];
    const float* W      = (const float*)d_in[1];
    const float* attn_l = (const float*)d_in[2];
    const float* attn_r = (const float*)d_in[3];
    const float* bias   = (const float*)d_in[4];
    const int*   src    = (const int*)d_in[5];
    const int*   dst    = (const int*)d_in[6];

    const int N  = in_sizes[0] / 128;
    const int E  = in_sizes[5];
    const int N8 = (N + 7) / 8;
    const int CH = (E + CHUNK - 1) / CHUNK;    // fill chunks
    const int GB = (N + 63) / 64;              // gemm blocks

    float* out = (float*)d_out;
    char*  ws  = (char*)d_ws;
    unsigned short* Wbf = (unsigned short*)ws;         ws += 128 * 128 * 2;
    unsigned short* h = (unsigned short*)ws;           ws += (size_t)N * 128 * 2;
    unsigned char* h8 = (unsigned char*)ws;            ws += (size_t)N * 128;
    float* el      = (float*)ws;                       ws += (size_t)N * 8 * 4;
    float* er      = (float*)ws;                       ws += (size_t)N * 8 * 4;
    int*   cnt     = (int*)ws;                         ws += (size_t)N * 4;
    int*   bins    = (int*)ws;                         ws += (size_t)N * BINW * 4;

    k_wt   <<<16,           256, 0, stream>>>(W, Wbf, cnt, N);
    k_gemm <<<GB,           256, 0, stream>>>(feats, Wbf, h, attn_l, attn_r, el, er, h8, N);
    k_fill <<<CH * 8,       256, 0, stream>>>(src, dst, cnt, bins, E, N8);
    k_agg  <<<(N + 3) / 4,  256, 0, stream>>>(cnt, bins, el, er, h8, h, bias, out, N);
}

// Round 10
// 267.605 us; speedup vs baseline: 1.2854x; 1.0536x over previous
//
#include <hip/hip_runtime.h>

#define NEG 0.2f
#define BINW 48      // bin slots per node; P(Poisson(16) >= 48) ~ 6e-11

using bf16x8 = __attribute__((ext_vector_type(8))) short;
using f32x4  = __attribute__((ext_vector_type(4))) float;
using f32x2  = __attribute__((ext_vector_type(2))) float;
using u32x4  = __attribute__((ext_vector_type(4))) unsigned int;

__device__ __forceinline__ short f2bf(float f) {   // RNE round to bf16 bits
    union { float f; unsigned u; } v; v.f = f;
    unsigned r = v.u + 0x7FFFu + ((v.u >> 16) & 1u);
    return (short)(r >> 16);
}
__device__ __forceinline__ float bflo(unsigned v) {
    union { unsigned u; float f; } x; x.u = v << 16; return x.f;
}
__device__ __forceinline__ float bfhi(unsigned v) {
    union { unsigned u; float f; } x; x.u = v & 0xffff0000u; return x.f;
}

// ---------------------------------------------------------------------------
// k_wt: W (f32, [k][c]) -> bf16 transposed Wbf[c*128+k] (16 blocks), plus
// grid-stride zeroing of cnt (replaces the hipMemsetAsync dispatch).
// ---------------------------------------------------------------------------
__global__ __launch_bounds__(256) void k_wt(const float* __restrict__ W,
                                            unsigned short* __restrict__ Wbf,
                                            int* __restrict__ cnt, int N) {
    int idx = (blockIdx.x * 256 + threadIdx.x) * 4;
    #pragma unroll
    for (int q = 0; q < 4; ++q) {
        int i = idx + q;            // i = k*128 + c
        int k = i >> 7, c = i & 127;
        Wbf[c * 128 + k] = (unsigned short)f2bf(W[i]);
    }
    for (int i = blockIdx.x * 256 + threadIdx.x; i < N; i += gridDim.x * 256)
        cnt[i] = 0;
}

// ---------------------------------------------------------------------------
// k_fg (FUSED fill+gemm, round-2 failure causes fixed):
//
// Blocks [0,FB): partitioned bin build, UNCHANGED from the measured 84 µs
// version (r = b&7 dst-range -> XCD-local cnt/bins lines; NT dst/src loads).
// Fill blocks dispatch FIRST. At 512 thr/block the 34.8 KB LDS allocation
// no longer costs fill occupancy: 3 blocks/CU x 8 waves = 24 waves/CU
// (round-2's 256-thr fusion gave only 16 — that was the regression).
// Fill is 5% VALU / 18% HBM / 0 MFMA (measured), so gemm blocks backfill
// its latency bubbles nearly for free.
//
// Blocks [FB,FB+GB): 2 x 64-row GEMM tiles per block sharing ONE Wt staging
// (h = bf16(feats) @ W via mfma_f32_16x16x32_bf16), then the fused epilogue
// (coalesced uint4 h stores, fp8 h8 pack, el/er dots) through the
// barrier-guarded reuse of Wt as two h-tiles (2 x 64 x 136 shorts = exactly
// Wt's 34816 B, contiguous: row128*136).
// ---------------------------------------------------------------------------
__global__ __launch_bounds__(512) void k_fg(const float* __restrict__ feats,
                                            const unsigned short* __restrict__ Wbf,
                                            unsigned short* __restrict__ h,
                                            const float* __restrict__ attn_l,
                                            const float* __restrict__ attn_r,
                                            float* __restrict__ el,
                                            float* __restrict__ er,
                                            unsigned char* __restrict__ h8,
                                            const int* __restrict__ src,
                                            const int* __restrict__ dst,
                                            int* __restrict__ cnt,
                                            int* __restrict__ bins,
                                            int N, int E, int N8, int FB) {
    __shared__ __align__(16) short Wt[128 * 136];   // 34816 B; reused as 2 h-tiles

    if (blockIdx.x < FB) {
        // ---- fill path (no LDS use, no barriers) ----
        int b = blockIdx.x;
        int r = b & 7;
        int c = b >> 3;
        int lo = r * N8, hi = lo + N8;
        int base = c * 4096 + threadIdx.x;
        #pragma unroll
        for (int q = 0; q < 8; ++q) {
            int e = base + q * 512;
            if (e < E) {
                int d = __builtin_nontemporal_load(dst + e);
                if (d >= lo && d < hi) {
                    int s = __builtin_nontemporal_load(src + e);
                    int p = atomicAdd(&cnt[d], 1);
                    if (p < BINW) bins[(size_t)d * BINW + p] = s;
                }
            }
        }
        return;
    }

    // ---- gemm path: 2 subtiles of 64 rows ----
    const int t   = threadIdx.x;
    const int gb  = blockIdx.x - FB;
    const int sub = t >> 8;         // 0,1
    const int tl  = t & 255;
    const int n0  = gb * 128 + sub * 64;

    {   // Wt cooperative load: 2048 uint4 over 512 threads
        const uint4* Ws = (const uint4*)Wbf;
        #pragma unroll
        for (int i = 0; i < 4; ++i) {
            int g = t * 4 + i;            // uint4 index
            int c = g >> 4, j = g & 15;   // row c, 16 uint4 per row
            *(uint4*)&Wt[c * 136 + j * 8] = Ws[g];
        }
    }
    __syncthreads();

    const int w    = tl >> 6;
    const int lane = tl & 63;
    const int m    = lane & 15;
    const int quad = lane >> 4;
    const int kq   = quad * 8;

    const int row_a = n0 + w * 16 + m;
    const bool va = (row_a < N);

    f32x4 acc[8];
    #pragma unroll
    for (int ti = 0; ti < 8; ++ti) acc[ti] = (f32x4){0.f, 0.f, 0.f, 0.f};

    #pragma unroll
    for (int kc = 0; kc < 4; ++kc) {
        const f32x4* ap = (const f32x4*)(feats + (size_t)row_a * 128 + kc * 32 + kq);
        f32x4 a0 = (f32x4){0.f,0.f,0.f,0.f}, a1 = (f32x4){0.f,0.f,0.f,0.f};
        if (va) {
            a0 = __builtin_nontemporal_load(ap);
            a1 = __builtin_nontemporal_load(ap + 1);
        }
        bf16x8 af;
        af[0] = f2bf(a0[0]); af[1] = f2bf(a0[1]); af[2] = f2bf(a0[2]); af[3] = f2bf(a0[3]);
        af[4] = f2bf(a1[0]); af[5] = f2bf(a1[1]); af[6] = f2bf(a1[2]); af[7] = f2bf(a1[3]);
        #pragma unroll
        for (int ti = 0; ti < 8; ++ti) {
            bf16x8 bf = *(const bf16x8*)&Wt[(ti * 16 + m) * 136 + kc * 32 + kq];
            acc[ti] = __builtin_amdgcn_mfma_f32_16x16x32_bf16(af, bf, acc[ti], 0, 0, 0);
        }
    }

    // ---- fused epilogue ----
    __syncthreads();                  // ALL subs' Wt reads complete before reuse
    // h-tile for sub s occupies Wt[s*8704 .. ), i.e. combined row128*136
    short* hsb = Wt + sub * (64 * 136);
    const int row_l = w * 16 + quad * 4;
    // C layout: col = ti*16 + m, row = row_l + r
    #pragma unroll
    for (int ti = 0; ti < 8; ++ti) {
        int col = ti * 16 + m;
        #pragma unroll
        for (int r = 0; r < 4; ++r)
            hsb[(row_l + r) * 136 + col] = f2bf(acc[ti][r]);
    }
    __syncthreads();

    #pragma unroll
    for (int u = 0; u < 2; ++u) {
        int pp = u * 512 + t;          // 1024 (row,head) pairs, 2 per thread
        int row128 = pp >> 3, hd = pp & 7;
        int rg = gb * 128 + row128;
        if (rg < N) {
            const uint4* hp = (const uint4*)&Wt[row128 * 136 + hd * 16];
            uint4 u0 = hp[0], u1 = hp[1];

            // coalesced bf16 h store (32 B per thread)
            uint4* hg = (uint4*)(h + (size_t)rg * 128 + hd * 16);
            hg[0] = u0; hg[1] = u1;

            float hv[16];
            hv[0]=bflo(u0.x); hv[1]=bfhi(u0.x); hv[2]=bflo(u0.y); hv[3]=bfhi(u0.y);
            hv[4]=bflo(u0.z); hv[5]=bfhi(u0.z); hv[6]=bflo(u0.w); hv[7]=bfhi(u0.w);
            hv[8]=bflo(u1.x); hv[9]=bfhi(u1.x); hv[10]=bflo(u1.y); hv[11]=bfhi(u1.y);
            hv[12]=bflo(u1.z); hv[13]=bfhi(u1.z); hv[14]=bflo(u1.w); hv[15]=bfhi(u1.w);

            // fp8 gather copy: 16 values -> 16 bytes, coalesced uint4 store
            unsigned p0 = 0, p1 = 0, p2 = 0, p3 = 0;
            p0 = __builtin_amdgcn_cvt_pk_fp8_f32(hv[0],  hv[1],  p0, false);
            p0 = __builtin_amdgcn_cvt_pk_fp8_f32(hv[2],  hv[3],  p0, true);
            p1 = __builtin_amdgcn_cvt_pk_fp8_f32(hv[4],  hv[5],  p1, false);
            p1 = __builtin_amdgcn_cvt_pk_fp8_f32(hv[6],  hv[7],  p1, true);
            p2 = __builtin_amdgcn_cvt_pk_fp8_f32(hv[8],  hv[9],  p2, false);
            p2 = __builtin_amdgcn_cvt_pk_fp8_f32(hv[10], hv[11], p2, true);
            p3 = __builtin_amdgcn_cvt_pk_fp8_f32(hv[12], hv[13], p3, false);
            p3 = __builtin_amdgcn_cvt_pk_fp8_f32(hv[14], hv[15], p3, true);
            *(uint4*)(h8 + (size_t)rg * 128 + hd * 16) = make_uint4(p0, p1, p2, p3);

            const float4* al = (const float4*)(attn_l + hd * 16);
            const float4* ar = (const float4*)(attn_r + hd * 16);
            float sl = 0.f, sr = 0.f;
            #pragma unroll
            for (int q = 0; q < 4; ++q) {
                float4 a = al[q], b = ar[q];
                sl += hv[4*q]*a.x + hv[4*q+1]*a.y + hv[4*q+2]*a.z + hv[4*q+3]*a.w;
                sr += hv[4*q]*b.x + hv[4*q+1]*b.y + hv[4*q+2]*b.z + hv[4*q+3]*b.w;
            }
            el[rg * 8 + hd] = sl;
            er[rg * 8 + hd] = sr;
        }
    }
}

// ---------------------------------------------------------------------------
// k_agg: gather aggregation, one wave per node; quarter q handles bin slots
// q, q+4, ... with 4-edge unroll. Message gather from fp8 h8 (8 B/lane,
// 128 B/edge); residual from bf16 h. Bin layout: bins[n*48 + slot],
// degree = min(cnt[n], 48). Block swizzle aligns node-range-eighth r with
// XCD r — the XCD whose L2 holds that range's bins lines from the fill.
// NT on touch-once traffic (bins, residual h, out stores) so L2 is kept
// for the reused h8/el gather lines.
// ---------------------------------------------------------------------------
__global__ __launch_bounds__(256) void k_agg(const int* __restrict__ cnt,
                                             const int* __restrict__ bins,
                                             const float* __restrict__ el,
                                             const float* __restrict__ er,
                                             const unsigned char* __restrict__ h8,
                                             const unsigned short* __restrict__ h,
                                             const float* __restrict__ bias,
                                             float* __restrict__ out, int N) {
    int nb = gridDim.x;
    int b  = blockIdx.x;
    int g  = ((nb & 7) == 0) ? ((b & 7) * (nb >> 3) + (b >> 3)) : b;

    int t = threadIdx.x;
    int n = g * 4 + (t >> 6);
    if (n >= N) return;
    int lane = t & 63;
    int q    = lane >> 4;      // slot phase 0..3
    int c16  = lane & 15;      // col group: cols 8*c16..8*c16+7
    int hd   = c16 >> 1;
    int deg  = cnt[n];
    if (deg > BINW) deg = BINW;
    int begin = n * BINW;
    int end   = begin + deg;
    float erv = er[n * 8 + hd];

    float acc[8] = {0.f,0.f,0.f,0.f,0.f,0.f,0.f,0.f};
    float expsum = 0.f;

    auto edge = [&](int p) {
        int s = __builtin_nontemporal_load(bins + p);
        float x = el[s * 8 + hd] + erv;
        x = x > 0.f ? x : NEG * x;
        float w = __expf(x);
        expsum += w;
        uint2 hv = *(const uint2*)(h8 + (size_t)s * 128 + c16 * 8);
        f32x2 d0 = __builtin_amdgcn_cvt_pk_f32_fp8(hv.x, false);
        f32x2 d1 = __builtin_amdgcn_cvt_pk_f32_fp8(hv.x, true);
        f32x2 d2 = __builtin_amdgcn_cvt_pk_f32_fp8(hv.y, false);
        f32x2 d3 = __builtin_amdgcn_cvt_pk_f32_fp8(hv.y, true);
        acc[0] += w * d0[0]; acc[1] += w * d0[1];
        acc[2] += w * d1[0]; acc[3] += w * d1[1];
        acc[4] += w * d2[0]; acc[5] += w * d2[1];
        acc[6] += w * d3[0]; acc[7] += w * d3[1];
    };

    int p = begin + q;
    for (; p + 12 < end; p += 16) { edge(p); edge(p + 4); edge(p + 8); edge(p + 12); }
    for (; p < end; p += 4) edge(p);

    #pragma unroll
    for (int k = 0; k < 8; ++k) {
        acc[k] += __shfl_xor(acc[k], 32);
        acc[k] += __shfl_xor(acc[k], 16);
    }
    expsum += __shfl_xor(expsum, 32);
    expsum += __shfl_xor(expsum, 16);

    if (q == 0) {
        float inv = expsum > 0.f ? 1.f / expsum : 0.f;
        u32x4 hn = __builtin_nontemporal_load((const u32x4*)(h + (size_t)n * 128 + c16 * 8));
        const float4* bp = (const float4*)(bias + c16 * 8);
        float4 b0 = bp[0], b1 = bp[1];
        f32x4 o0, o1;
        o0[0] = acc[0]*inv + bflo(hn[0]) + b0.x;
        o0[1] = acc[1]*inv + bfhi(hn[0]) + b0.y;
        o0[2] = acc[2]*inv + bflo(hn[1]) + b0.z;
        o0[3] = acc[3]*inv + bfhi(hn[1]) + b0.w;
        o1[0] = acc[4]*inv + bflo(hn[2]) + b1.x;
        o1[1] = acc[5]*inv + bfhi(hn[2]) + b1.y;
        o1[2] = acc[6]*inv + bflo(hn[3]) + b1.z;
        o1[3] = acc[7]*inv + bfhi(hn[3]) + b1.w;
        f32x4* op = (f32x4*)(out + (size_t)n * 128 + c16 * 8);
        __builtin_nontemporal_store(o0, op);
        __builtin_nontemporal_store(o1, op + 1);
    }
}

extern "C" void kernel_launch(void* const* d_in, const int* in_sizes, int n_in,
                              void* d_out, int out_size, void* d_ws, size_t ws_size,
                              hipStream_t stream) {
    const float* feats  = (const float*)d_in[0];
    const float* W      = (const float*)d_in[1];
    const float* attn_l = (const float*)d_in[2];
    const float* attn_r = (const float*)d_in[3];
    const float* bias   = (const float*)d_in[4];
    const int*   src    = (const int*)d_in[5];
    const int*   dst    = (const int*)d_in[6];

    const int N  = in_sizes[0] / 128;
    const int E  = in_sizes[5];
    const int N8 = (N + 7) / 8;
    const int FB = ((E + 4095) / 4096) * 8;    // fill blocks (4096 edges each, x8 ranges)
    const int GB = (N + 127) / 128;            // gemm blocks (128 rows each)

    float* out = (float*)d_out;
    char*  ws  = (char*)d_ws;
    unsigned short* Wbf = (unsigned short*)ws;         ws += 128 * 128 * 2;
    unsigned short* h = (unsigned short*)ws;           ws += (size_t)N * 128 * 2;
    unsigned char* h8 = (unsigned char*)ws;            ws += (size_t)N * 128;
    float* el      = (float*)ws;                       ws += (size_t)N * 8 * 4;
    float* er      = (float*)ws;                       ws += (size_t)N * 8 * 4;
    int*   cnt     = (int*)ws;                         ws += (size_t)N * 4;
    int*   bins    = (int*)ws;                         ws += (size_t)N * BINW * 4;

    k_wt  <<<16,           256, 0, stream>>>(W, Wbf, cnt, N);
    k_fg  <<<FB + GB,      512, 0, stream>>>(feats, Wbf, h, attn_l, attn_r, el, er, h8,
                                             src, dst, cnt, bins, N, E, N8, FB);
    k_agg <<<(N + 3) / 4,  256, 0, stream>>>(cnt, bins, el, er, h8, h, bias, out, N);
}